// Round 12
// baseline (563.053 us; speedup 1.0000x reference)
//
#include <hip/hip_runtime.h>

// SelfInteraction on MI355X.
// R11: ABLATION ROUND. V2 = B-loads only; V1 = compute only (constant B); V0 = R10
// unmodified (runs last, owns the output). Per-dispatch dur_us isolates the stall.

#define C 128
#define NBATCH 8192

typedef _Float16 f16;
typedef _Float16 f16x8 __attribute__((ext_vector_type(8)));
typedef float f32x16 __attribute__((ext_vector_type(16)));
typedef unsigned int u32;

#define WSTREAM_F16_PER_C 2097152             // 4 MB per stream
#define HQSL 524288                           // f16 per hq quarter (1 MB)
#define USL 4096                              // f16 per u-step slice (8 KB)
#define NSTREAM 3
#define RAW_OFF_BYTES ((size_t)NSTREAM*WSTREAM_F16_PER_C*2)  // 12 MB
#define PSTR 136               // f16/row: 272B -> b128-aligned rows
#define PLSZ (128*PSTR + 8)    // x-plane stride (f16)

__device__ __forceinline__ f16x8 splat8(f16 v) { return (f16x8){v, v, v, v, v, v, v, v}; }
union U16x8 { uint4 u; f16x8 h; };
__device__ __forceinline__ f16x8 as_h8(uint4 v) { U16x8 x; x.u = v; return x.h; }
__device__ __forceinline__ f32x16 mfma32(f16x8 a, f16x8 b, f32x16 c) {
    return __builtin_amdgcn_mfma_f32_32x32x16_f16(a, b, c, 0, 0, 0);
}

// ---------------- weight prep (unchanged) ----------------
__global__ __launch_bounds__(256) void prep_weights(
        const float* __restrict__ Wss, const float* __restrict__ Wvv,
        const float* __restrict__ Wsv, const float* __restrict__ Wvs,
        f16* __restrict__ out) {
    __shared__ float lds[128 * 130];
    int c = blockIdx.x >> 7;
    int u = blockIdx.x & 127;
    if (c == 2) {
        for (int i = threadIdx.x; i < 16384; i += 256) {
            int v = i >> 7, w = i & 127;
            lds[v * 130 + w] = Wsv[(size_t)u * 16384 + i] + Wvs[(size_t)v * 16384 + u * 128 + w];
        }
    } else {
        const float* src = (c == 0 ? Wss : Wvv) + (size_t)u * 16384;
        float sc = (c == 0) ? 1.0f : 0.57735026918962576f;
        for (int i = threadIdx.x; i < 16384; i += 256) {
            int v = i >> 7, w = i & 127;
            lds[v * 130 + w] = sc * src[i];
        }
    }
    __syncthreads();
    f16* dst = out + (size_t)c * WSTREAM_F16_PER_C;
    for (int pos = threadIdx.x; pos < 2048; pos += 256) {
        int hq = pos >> 9, vb = (pos >> 7) & 3, kt = (pos >> 6) & 1, l = pos & 63;
        int v0 = vb * 32 + kt * 16 + ((l >> 5) << 3);
        int w = hq * 32 + (l & 31);
        f16x8 vals;
#pragma unroll
        for (int j = 0; j < 8; ++j) vals[j] = (f16)lds[(v0 + j) * 130 + w];
        size_t off = (size_t)hq * HQSL + (size_t)u * USL + (size_t)(vb * 2 + kt) * 512
                   + (size_t)l * 8;
        *(f16x8*)(dst + off) = vals;
    }
}

__device__ __forceinline__ void writeT32(float* __restrict__ raw, int c, int zrow0,
        int col0, int l31, int lk, const f32x16& a, bool st) {
#pragma unroll
    for (int reg = 0; reg < 16; ++reg) {
        int row = (reg & 3) + 8 * (reg >> 2) + 4 * lk;
        float* p = &raw[((size_t)c * NBATCH + zrow0 + row) * 128 + col0 + l31];
        if (st) *p = a[reg]; else *p += a[reg];
    }
}

// ---------------- V0: unmodified R10 main kernel ----------------
__global__ __launch_bounds__(1024, 4) void si_main(
        const float* __restrict__ x, const f16* __restrict__ wstream,
        float* __restrict__ raw) {
    __shared__ f16 xp[4 * PLSZ];

    int zb = blockIdx.x >> 2;
    int hq = blockIdx.x & 3;
    int tid = threadIdx.x;

    const f16* sA = wstream + (size_t)hq * HQSL;
    const f16* sB = wstream + WSTREAM_F16_PER_C + (size_t)hq * HQSL;
    const f16* sC = wstream + (size_t)2 * WSTREAM_F16_PER_C + (size_t)hq * HQSL;

    for (int i = tid; i < 128 * 512; i += 1024) {
        int z = i >> 9, col = i & 511;
        f16 fv = (f16)x[(size_t)(zb * 128 + z) * 512 + col];
        if (col < 128) {
            xp[z * PSTR + col] = fv;
        } else {
            int cc = col - 128;
            int v = cc / 3, k = cc - v * 3;
            xp[(1 + k) * PLSZ + z * PSTR + v] = fv;
        }
    }
    __syncthreads();

    int lane = tid & 63, w = tid >> 6;
    int l31 = lane & 31, lk = lane >> 5;

    int mg = w >> 3, vb = (w >> 1) & 3, kt = w & 1;
    const int rm0 = (mg * 64 + l31) * PSTR, rm1 = rm0 + 32 * PSTR;
    f32x16 accA = {}, accB = {};
    {
        const uint4* bl = (const uint4*)sA + (vb * 2 + kt) * 64 + lane;
        f16x8 va0 = *(const f16x8*)&xp[rm0 + vb * 32 + kt * 16 + lk * 8];
        f16x8 va1 = *(const f16x8*)&xp[rm1 + vb * 32 + kt * 16 + lk * 8];
        uint4 B0 = bl[0], B1 = bl[512], B2 = bl[1024], B3 = bl[1536];
        for (int g = 0; g < 16; ++g) {
            f16x8 s0v = *(const f16x8*)&xp[rm0 + g * 8];
            f16x8 s1v = *(const f16x8*)&xp[rm1 + g * 8];
#define SS_STEP(j, Bq)                                                  \
            {                                                           \
                accA = mfma32(splat8(s0v[j]) * va0, as_h8(Bq), accA);   \
                accB = mfma32(splat8(s1v[j]) * va1, as_h8(Bq), accB);   \
                int u_ = g * 8 + j;                                     \
                int up_ = u_ + 4 < 128 ? u_ + 4 : 127;                  \
                Bq = bl[(size_t)up_ * 512];                             \
            }
            SS_STEP(0, B0) SS_STEP(1, B1) SS_STEP(2, B2) SS_STEP(3, B3)
            SS_STEP(4, B0) SS_STEP(5, B1) SS_STEP(6, B2) SS_STEP(7, B3)
#undef SS_STEP
        }
    }
#pragma unroll
    for (int r = 0; r < 8; ++r) {
        __threadfence_block();
        __syncthreads();
        if ((vb * 2 + kt) == r) {
            writeT32(raw, 0, zb * 128 + mg * 64,      hq * 32, l31, lk, accA, r == 0);
            writeT32(raw, 0, zb * 128 + mg * 64 + 32, hq * 32, l31, lk, accB, r == 0);
        }
    }

    f32x16 accVA = {}, accVB = {};
    {
        const uint4* bl = (const uint4*)sB + (vb * 2 + kt) * 64 + lane;
        f16x8 wa0[3], wa1[3];
#pragma unroll
        for (int p = 0; p < 3; ++p) {
            wa0[p] = *(const f16x8*)&xp[(1 + p) * PLSZ + rm0 + vb * 32 + kt * 16 + lk * 8];
            wa1[p] = *(const f16x8*)&xp[(1 + p) * PLSZ + rm1 + vb * 32 + kt * 16 + lk * 8];
        }
        uint4 B0 = bl[0], B1 = bl[512], B2 = bl[1024], B3 = bl[1536];
        for (int g = 0; g < 16; ++g) {
            f16x8 p00 = *(const f16x8*)&xp[1 * PLSZ + rm0 + g * 8];
            f16x8 p01 = *(const f16x8*)&xp[2 * PLSZ + rm0 + g * 8];
            f16x8 p02 = *(const f16x8*)&xp[3 * PLSZ + rm0 + g * 8];
            f16x8 p10 = *(const f16x8*)&xp[1 * PLSZ + rm1 + g * 8];
            f16x8 p11 = *(const f16x8*)&xp[2 * PLSZ + rm1 + g * 8];
            f16x8 p12 = *(const f16x8*)&xp[3 * PLSZ + rm1 + g * 8];
#define VV_STEP(j, Bq)                                                  \
            {                                                           \
                f16x8 A0 = splat8(p00[j]) * wa0[0]                      \
                         + splat8(p01[j]) * wa0[1]                      \
                         + splat8(p02[j]) * wa0[2];                     \
                f16x8 A1 = splat8(p10[j]) * wa1[0]                      \
                         + splat8(p11[j]) * wa1[1]                      \
                         + splat8(p12[j]) * wa1[2];                     \
                accVA = mfma32(A0, as_h8(Bq), accVA);                   \
                accVB = mfma32(A1, as_h8(Bq), accVB);                   \
                int u_ = g * 8 + j;                                     \
                int up_ = u_ + 4 < 128 ? u_ + 4 : 127;                  \
                Bq = bl[(size_t)up_ * 512];                             \
            }
            VV_STEP(0, B0) VV_STEP(1, B1) VV_STEP(2, B2) VV_STEP(3, B3)
            VV_STEP(4, B0) VV_STEP(5, B1) VV_STEP(6, B2) VV_STEP(7, B3)
#undef VV_STEP
        }
    }
#pragma unroll
    for (int r = 0; r < 8; ++r) {
        __threadfence_block();
        __syncthreads();
        if ((vb * 2 + kt) == r) {
            writeT32(raw, 1, zb * 128 + mg * 64,      hq * 32, l31, lk, accVA, r == 0);
            writeT32(raw, 1, zb * 128 + mg * 64 + 32, hq * 32, l31, lk, accVB, r == 0);
        }
    }

    int mgc = w >> 2, vbc = w & 3;
    const int rowm = (mgc * 32 + l31) * PSTR;
    f32x16 acc2[3] = {};
    {
        const uint4* bl = (const uint4*)sC + (vbc * 2) * 64 + lane;
        f16x8 vvb[3][2];
#pragma unroll
        for (int p = 0; p < 3; ++p)
#pragma unroll
            for (int tt = 0; tt < 2; ++tt)
                vvb[p][tt] = *(const f16x8*)&xp[(1 + p) * PLSZ + rowm
                                                + vbc * 32 + tt * 16 + lk * 8];
        uint4 C00 = bl[0],   C01 = bl[64];
        uint4 C10 = bl[512], C11 = bl[576];
        for (int g = 0; g < 16; ++g) {
            f16x8 spv = *(const f16x8*)&xp[rowm + g * 8];
#define CB_STEP(j, Ca, Cb)                                              \
            {                                                           \
                f16x8 sp = splat8(spv[j]);                              \
                acc2[0] = mfma32(sp * vvb[0][0], as_h8(Ca), acc2[0]);   \
                acc2[0] = mfma32(sp * vvb[0][1], as_h8(Cb), acc2[0]);   \
                acc2[1] = mfma32(sp * vvb[1][0], as_h8(Ca), acc2[1]);   \
                acc2[1] = mfma32(sp * vvb[1][1], as_h8(Cb), acc2[1]);   \
                acc2[2] = mfma32(sp * vvb[2][0], as_h8(Ca), acc2[2]);   \
                acc2[2] = mfma32(sp * vvb[2][1], as_h8(Cb), acc2[2]);   \
                int u_ = g * 8 + j;                                     \
                int up_ = u_ + 2 < 128 ? u_ + 2 : 127;                  \
                Ca = bl[(size_t)up_ * 512];                             \
                Cb = bl[(size_t)up_ * 512 + 64];                        \
            }
            CB_STEP(0, C00, C01) CB_STEP(1, C10, C11)
            CB_STEP(2, C00, C01) CB_STEP(3, C10, C11)
            CB_STEP(4, C00, C01) CB_STEP(5, C10, C11)
            CB_STEP(6, C00, C01) CB_STEP(7, C10, C11)
#undef CB_STEP
        }
    }
#pragma unroll
    for (int r = 0; r < 4; ++r) {
        __threadfence_block();
        __syncthreads();
        int k = (vbc - r) & 3;
        if (k == 0)      writeT32(raw, 2, zb * 128 + mgc * 32, hq * 32, l31, lk, acc2[0], r == 0);
        else if (k == 1) writeT32(raw, 3, zb * 128 + mgc * 32, hq * 32, l31, lk, acc2[1], r == 0);
        else if (k == 2) writeT32(raw, 4, zb * 128 + mgc * 32, hq * 32, l31, lk, acc2[2], r == 0);
    }
}

// ---------------- ablation kernels ----------------
// VAR==1: compute-only (B = constant, NO global B loads).  VAR==2: B-loads only
// (identical addresses/pattern, consumed by integer sums, no MFMA/A-build).
// Both write into raw scratch; si_main runs AFTER and overwrites all of raw.
template<int VAR>
__global__ __launch_bounds__(1024, 4) void si_ablate(
        const float* __restrict__ x, const f16* __restrict__ wstream,
        float* __restrict__ raw) {
    __shared__ f16 xp[4 * PLSZ];

    int zb = blockIdx.x >> 2;
    int hq = blockIdx.x & 3;
    int tid = threadIdx.x;

    const f16* sA = wstream + (size_t)hq * HQSL;
    const f16* sB = wstream + WSTREAM_F16_PER_C + (size_t)hq * HQSL;
    const f16* sC = wstream + (size_t)2 * WSTREAM_F16_PER_C + (size_t)hq * HQSL;

    for (int i = tid; i < 128 * 512; i += 1024) {
        int z = i >> 9, col = i & 511;
        f16 fv = (f16)x[(size_t)(zb * 128 + z) * 512 + col];
        if (col < 128) {
            xp[z * PSTR + col] = fv;
        } else {
            int cc = col - 128;
            int v = cc / 3, k = cc - v * 3;
            xp[(1 + k) * PLSZ + z * PSTR + v] = fv;
        }
    }
    __syncthreads();

    int lane = tid & 63, w = tid >> 6;
    int l31 = lane & 31, lk = lane >> 5;

    const uint4 KB = {0x3c003c00u, 0x3c003c00u, 0x3c003c00u, 0x3c003c00u};  // f16 1.0s
    u32 vsum = 0;

    int mg = w >> 3, vb = (w >> 1) & 3, kt = w & 1;
    const int rm0 = (mg * 64 + l31) * PSTR, rm1 = rm0 + 32 * PSTR;
    f32x16 accA = {}, accB = {};

    // ---- ss ----
    if constexpr (VAR == 1) {
        f16x8 va0 = *(const f16x8*)&xp[rm0 + vb * 32 + kt * 16 + lk * 8];
        f16x8 va1 = *(const f16x8*)&xp[rm1 + vb * 32 + kt * 16 + lk * 8];
        for (int g = 0; g < 16; ++g) {
            f16x8 s0v = *(const f16x8*)&xp[rm0 + g * 8];
            f16x8 s1v = *(const f16x8*)&xp[rm1 + g * 8];
#pragma unroll
            for (int j = 0; j < 8; ++j) {
                accA = mfma32(splat8(s0v[j]) * va0, as_h8(KB), accA);
                accB = mfma32(splat8(s1v[j]) * va1, as_h8(KB), accB);
            }
        }
    } else {
        const uint4* bl = (const uint4*)sA + (vb * 2 + kt) * 64 + lane;
        uint4 B0 = bl[0], B1 = bl[512], B2 = bl[1024], B3 = bl[1536];
        for (int g = 0; g < 16; ++g) {
#define SS_L(j, Bq)                                                     \
            {                                                           \
                vsum += Bq.x + Bq.w;                                    \
                int u_ = g * 8 + j;                                     \
                int up_ = u_ + 4 < 128 ? u_ + 4 : 127;                  \
                Bq = bl[(size_t)up_ * 512];                             \
            }
            SS_L(0, B0) SS_L(1, B1) SS_L(2, B2) SS_L(3, B3)
            SS_L(4, B0) SS_L(5, B1) SS_L(6, B2) SS_L(7, B3)
#undef SS_L
        }
        vsum += B0.x + B1.x + B2.x + B3.x;
    }
#pragma unroll
    for (int r = 0; r < 8; ++r) {
        __threadfence_block();
        __syncthreads();
        if (VAR == 1 && (vb * 2 + kt) == r) {
            writeT32(raw, 0, zb * 128 + mg * 64,      hq * 32, l31, lk, accA, r == 0);
            writeT32(raw, 0, zb * 128 + mg * 64 + 32, hq * 32, l31, lk, accB, r == 0);
        }
    }

    // ---- vv ----
    f32x16 accVA = {}, accVB = {};
    if constexpr (VAR == 1) {
        f16x8 wa0[3], wa1[3];
#pragma unroll
        for (int p = 0; p < 3; ++p) {
            wa0[p] = *(const f16x8*)&xp[(1 + p) * PLSZ + rm0 + vb * 32 + kt * 16 + lk * 8];
            wa1[p] = *(const f16x8*)&xp[(1 + p) * PLSZ + rm1 + vb * 32 + kt * 16 + lk * 8];
        }
        for (int g = 0; g < 16; ++g) {
            f16x8 p00 = *(const f16x8*)&xp[1 * PLSZ + rm0 + g * 8];
            f16x8 p01 = *(const f16x8*)&xp[2 * PLSZ + rm0 + g * 8];
            f16x8 p02 = *(const f16x8*)&xp[3 * PLSZ + rm0 + g * 8];
            f16x8 p10 = *(const f16x8*)&xp[1 * PLSZ + rm1 + g * 8];
            f16x8 p11 = *(const f16x8*)&xp[2 * PLSZ + rm1 + g * 8];
            f16x8 p12 = *(const f16x8*)&xp[3 * PLSZ + rm1 + g * 8];
#pragma unroll
            for (int j = 0; j < 8; ++j) {
                f16x8 A0 = splat8(p00[j]) * wa0[0] + splat8(p01[j]) * wa0[1]
                         + splat8(p02[j]) * wa0[2];
                f16x8 A1 = splat8(p10[j]) * wa1[0] + splat8(p11[j]) * wa1[1]
                         + splat8(p12[j]) * wa1[2];
                accVA = mfma32(A0, as_h8(KB), accVA);
                accVB = mfma32(A1, as_h8(KB), accVB);
            }
        }
    } else {
        const uint4* bl = (const uint4*)sB + (vb * 2 + kt) * 64 + lane;
        uint4 B0 = bl[0], B1 = bl[512], B2 = bl[1024], B3 = bl[1536];
        for (int g = 0; g < 16; ++g) {
#define VV_L(j, Bq)                                                     \
            {                                                           \
                vsum += Bq.y + Bq.z;                                    \
                int u_ = g * 8 + j;                                     \
                int up_ = u_ + 4 < 128 ? u_ + 4 : 127;                  \
                Bq = bl[(size_t)up_ * 512];                             \
            }
            VV_L(0, B0) VV_L(1, B1) VV_L(2, B2) VV_L(3, B3)
            VV_L(4, B0) VV_L(5, B1) VV_L(6, B2) VV_L(7, B3)
#undef VV_L
        }
        vsum += B0.y + B1.y + B2.y + B3.y;
    }
#pragma unroll
    for (int r = 0; r < 8; ++r) {
        __threadfence_block();
        __syncthreads();
        if (VAR == 1 && (vb * 2 + kt) == r) {
            writeT32(raw, 1, zb * 128 + mg * 64,      hq * 32, l31, lk, accVA, r == 0);
            writeT32(raw, 1, zb * 128 + mg * 64 + 32, hq * 32, l31, lk, accVB, r == 0);
        }
    }

    // ---- cb ----
    int mgc = w >> 2, vbc = w & 3;
    const int rowm = (mgc * 32 + l31) * PSTR;
    f32x16 acc2[3] = {};
    if constexpr (VAR == 1) {
        f16x8 vvb[3][2];
#pragma unroll
        for (int p = 0; p < 3; ++p)
#pragma unroll
            for (int tt = 0; tt < 2; ++tt)
                vvb[p][tt] = *(const f16x8*)&xp[(1 + p) * PLSZ + rowm
                                                + vbc * 32 + tt * 16 + lk * 8];
        for (int g = 0; g < 16; ++g) {
            f16x8 spv = *(const f16x8*)&xp[rowm + g * 8];
#pragma unroll
            for (int j = 0; j < 8; ++j) {
                f16x8 sp = splat8(spv[j]);
#pragma unroll
                for (int k = 0; k < 3; ++k) {
                    acc2[k] = mfma32(sp * vvb[k][0], as_h8(KB), acc2[k]);
                    acc2[k] = mfma32(sp * vvb[k][1], as_h8(KB), acc2[k]);
                }
            }
        }
    } else {
        const uint4* bl = (const uint4*)sC + (vbc * 2) * 64 + lane;
        uint4 C00 = bl[0],   C01 = bl[64];
        uint4 C10 = bl[512], C11 = bl[576];
        for (int g = 0; g < 16; ++g) {
#define CB_L(j, Ca, Cb)                                                 \
            {                                                           \
                vsum += Ca.x + Cb.w;                                    \
                int u_ = g * 8 + j;                                     \
                int up_ = u_ + 2 < 128 ? u_ + 2 : 127;                  \
                Ca = bl[(size_t)up_ * 512];                             \
                Cb = bl[(size_t)up_ * 512 + 64];                        \
            }
            CB_L(0, C00, C01) CB_L(1, C10, C11)
            CB_L(2, C00, C01) CB_L(3, C10, C11)
            CB_L(4, C00, C01) CB_L(5, C10, C11)
            CB_L(6, C00, C01) CB_L(7, C10, C11)
#undef CB_L
        }
        vsum += C00.x + C01.x + C10.x + C11.x;
    }
#pragma unroll
    for (int r = 0; r < 4; ++r) {
        __threadfence_block();
        __syncthreads();
        int k = (vbc - r) & 3;
        if (VAR == 1 && k < 3)
            writeT32(raw, 2 + k, zb * 128 + mgc * 32, hq * 32, l31, lk, acc2[k < 3 ? k : 0], r == 0);
    }
    if constexpr (VAR == 2)
        raw[(size_t)blockIdx.x * 1024 + tid] = (float)vsum;   // scratch; overwritten by si_main
}

// ---------------- finalize (unchanged) ----------------
__global__ __launch_bounds__(64) void si_finalize(const float* __restrict__ raw,
                                                  float* __restrict__ out) {
    const float PW0 = 0.0055242717280199f;
    int z = blockIdx.x;
    int t = threadIdx.x;
    const size_t CS = (size_t)NBATCH * 128;
    const float* r0 = raw + (size_t)z * 128;

    float y0A = PW0 * (r0[t] + r0[CS + t]);
    float y0B = PW0 * (r0[t + 64] + r0[CS + t + 64]);
    float s1 = y0A + y0B, s2 = y0A * y0A + y0B * y0B;
    for (int o = 32; o; o >>= 1) {
        s1 += __shfl_xor(s1, o);
        s2 += __shfl_xor(s2, o);
    }
    float mean = s1 * (1.0f / 128.0f);
    float var = (s2 - 128.0f * mean * mean) * (1.0f / 127.0f);
    float sc = 1.0f / (sqrtf(fmaxf(var, 0.0f)) + 1e-9f);
    out[(size_t)z * 512 + t] = y0A * sc;
    out[(size_t)z * 512 + t + 64] = y0B * sc;

    float yA[3], yB[3];
    float nA = 1e-9f, nB = 1e-9f;
#pragma unroll
    for (int k = 0; k < 3; ++k) {
        yA[k] = PW0 * r0[CS * (2 + k) + t];
        yB[k] = PW0 * r0[CS * (2 + k) + t + 64];
        nA += yA[k] * yA[k];
        nB += yB[k] * yB[k];
    }
    nA = sqrtf(nA);
    nB = sqrtf(nB);
    float t1 = nA + nB, t2 = nA * nA + nB * nB;
    for (int o = 32; o; o >>= 1) {
        t1 += __shfl_xor(t1, o);
        t2 += __shfl_xor(t2, o);
    }
    float meanv = t1 * (1.0f / 128.0f);
    float varv = (t2 - 128.0f * meanv * meanv) * (1.0f / 127.0f);
    float sv = 1.0f / (sqrtf(fmaxf(varv, 0.0f)) + 1e-9f);
#pragma unroll
    for (int k = 0; k < 3; ++k) {
        out[(size_t)z * 512 + 128 + t * 3 + k] = yA[k] * sv;
        out[(size_t)z * 512 + 128 + (t + 64) * 3 + k] = yB[k] * sv;
    }
}

extern "C" void kernel_launch(void* const* d_in, const int* in_sizes, int n_in,
                              void* d_out, int out_size, void* d_ws, size_t ws_size,
                              hipStream_t stream) {
    const float* x = (const float*)d_in[0];
    const float* Wss = (const float*)d_in[1];
    const float* Wvv = (const float*)d_in[2];
    const float* Wsv = (const float*)d_in[3];
    const float* Wvs = (const float*)d_in[4];
    f16* wstream = (f16*)d_ws;
    float* raw = (float*)((char*)d_ws + RAW_OFF_BYTES);
    float* out = (float*)d_out;

    hipLaunchKernelGGL(prep_weights, dim3(384), dim3(256), 0, stream,
                       Wss, Wvv, Wsv, Wvs, wstream);
    hipLaunchKernelGGL(HIP_KERNEL_NAME(si_ablate<2>), dim3(256), dim3(1024), 0, stream,
                       x, wstream, raw);   // B-loads only
    hipLaunchKernelGGL(HIP_KERNEL_NAME(si_ablate<1>), dim3(256), dim3(1024), 0, stream,
                       x, wstream, raw);   // compute only
    hipLaunchKernelGGL(si_main, dim3(256), dim3(1024), 0, stream, x, wstream, raw);
    hipLaunchKernelGGL(si_finalize, dim3(NBATCH), dim3(64), 0, stream, raw, out);
}

// Round 13
// 436.448 us; speedup vs baseline: 1.2901x; 1.2901x over previous
//
#include <hip/hip_runtime.h>

// SelfInteraction on MI355X.
// R12: FULL-K PER WAVE — no cross-wave reduction, no RMW, no post-staging barriers.
// Grid 512 (128 zt x 4 hq), 640-thr blocks (10 waves), 2 blocks/CU (5 waves/SIMD).
// Waves: 2 ss + 2 vv + 6 cb, 1024 MFMA each; half-u ping-pong B prefetch; store once.

#define NBATCH 8192

typedef _Float16 f16;
typedef _Float16 f16x8 __attribute__((ext_vector_type(8)));
typedef float f32x16 __attribute__((ext_vector_type(16)));
typedef unsigned int u32;

// ws layout (unchanged):
// [0, 12MB)  : 3 f16 weight streams (ss, vv*inv_sqrt3, comb=Wsv+Wvs^T)
//              order [hq4][u128][seg8][lane64][j8], seg covers v in [seg*16, seg*16+16)
// [12MB,32MB): raw channel sums f32 [5][8192][128]
#define WSTREAM_F16_PER_C 2097152
#define HQSL 524288
#define USL 4096
#define RAW_OFF_BYTES ((size_t)3*WSTREAM_F16_PER_C*2)
#define PSTR 136               // 272B rows: b128-aligned
#define PLSZ (64*PSTR + 8)     // 64-row plane + 16B skew

__device__ __forceinline__ f16x8 splat8(f16 v) { return (f16x8){v, v, v, v, v, v, v, v}; }
union U16x8 { uint4 u; f16x8 h; };
__device__ __forceinline__ f16x8 as_h8(uint4 v) { U16x8 x; x.u = v; return x.h; }
__device__ __forceinline__ f32x16 mfma32(f16x8 a, f16x8 b, f32x16 c) {
    return __builtin_amdgcn_mfma_f32_32x32x16_f16(a, b, c, 0, 0, 0);
}

// ---------------- weight prep (unchanged layout) ----------------
__global__ __launch_bounds__(256) void prep_weights(
        const float* __restrict__ Wss, const float* __restrict__ Wvv,
        const float* __restrict__ Wsv, const float* __restrict__ Wvs,
        f16* __restrict__ out) {
    __shared__ float lds[128 * 130];
    int c = blockIdx.x >> 7;
    int u = blockIdx.x & 127;
    if (c == 2) {
        for (int i = threadIdx.x; i < 16384; i += 256) {
            int v = i >> 7, w = i & 127;
            lds[v * 130 + w] = Wsv[(size_t)u * 16384 + i] + Wvs[(size_t)v * 16384 + u * 128 + w];
        }
    } else {
        const float* src = (c == 0 ? Wss : Wvv) + (size_t)u * 16384;
        float sc = (c == 0) ? 1.0f : 0.57735026918962576f;
        for (int i = threadIdx.x; i < 16384; i += 256) {
            int v = i >> 7, w = i & 127;
            lds[v * 130 + w] = sc * src[i];
        }
    }
    __syncthreads();
    f16* dst = out + (size_t)c * WSTREAM_F16_PER_C;
    for (int pos = threadIdx.x; pos < 2048; pos += 256) {
        int hq = pos >> 9, vb = (pos >> 7) & 3, kt = (pos >> 6) & 1, l = pos & 63;
        int v0 = vb * 32 + kt * 16 + ((l >> 5) << 3);
        int w = hq * 32 + (l & 31);
        f16x8 vals;
#pragma unroll
        for (int j = 0; j < 8; ++j) vals[j] = (f16)lds[(v0 + j) * 130 + w];
        size_t off = (size_t)hq * HQSL + (size_t)u * USL + (size_t)(vb * 2 + kt) * 512
                   + (size_t)l * 8;
        *(f16x8*)(dst + off) = vals;
    }
}

// 32x32 C/D tile: row=(reg&3)+8*(reg>>2)+4*lk, col=l31  (store-once)
__device__ __forceinline__ void writeT32(float* __restrict__ raw, int c, int zrow0,
        int col0, int l31, int lk, const f32x16& a) {
#pragma unroll
    for (int reg = 0; reg < 16; ++reg) {
        int row = (reg & 3) + 8 * (reg >> 2) + 4 * lk;
        raw[((size_t)c * NBATCH + zrow0 + row) * 128 + col0 + l31] = a[reg];
    }
}

// ---------------- main kernel ----------------
// grid 512: zb = bid>>2 (64-row z-tile), hq = bid&3 (XCD-affine under %8).
// 640 thr = 10 waves: w0-1 ss(mg), w2-3 vv(mg), w4-9 cb(k=(w-4)>>1, mg=(w-4)&1).
// Each wave: full K=16384, one 32x32 tile, 1024 MFMA, store once. No barriers
// after staging, no reduction.
__global__ __launch_bounds__(640, 5) void si_main(
        const float* __restrict__ x, const f16* __restrict__ wstream,
        float* __restrict__ raw) {
    __shared__ f16 xp[4 * PLSZ];   // ~70 KB -> 2 blocks/CU

    int zb = blockIdx.x >> 2;
    int hq = blockIdx.x & 3;
    int tid = threadIdx.x;

    for (int i = tid; i < 64 * 512; i += 640) {
        int z = i >> 9, col = i & 511;
        f16 fv = (f16)x[(size_t)(zb * 64 + z) * 512 + col];
        if (col < 128) {
            xp[z * PSTR + col] = fv;
        } else {
            int cc = col - 128;
            int v = cc / 3, k = cc - v * 3;
            xp[(1 + k) * PLSZ + z * PSTR + v] = fv;
        }
    }
    __syncthreads();

    int lane = tid & 63, w = tid >> 6;
    int l31 = lane & 31, lk = lane >> 5;

    if (w < 2 || w >= 4) {
        // ---- rank-1 channels: ss (w0-1) and cb_k (w4-9) ----
        int mg, cidx;
        const f16 *pv;
        const f16 *st;
        if (w < 2) {
            mg = w; cidx = 0; pv = xp;
            st = wstream + (size_t)hq * HQSL;
        } else {
            int k = (w - 4) >> 1; mg = (w - 4) & 1;
            cidx = 2 + k; pv = xp + (1 + k) * PLSZ;
            st = wstream + (size_t)2 * WSTREAM_F16_PER_C + (size_t)hq * HQSL;
        }
        const int rm = (mg * 32 + l31) * PSTR;
        f16x8 va[8];
#pragma unroll
        for (int s = 0; s < 8; ++s)
            va[s] = *(const f16x8*)&pv[rm + s * 16 + lk * 8];

        const uint4* bl = (const uint4*)st + lane;
        f32x16 acc = {};
        uint4 P0 = bl[0],   P1 = bl[64],  P2 = bl[128], P3 = bl[192];
        uint4 Q0 = bl[256], Q1 = bl[320], Q2 = bl[384], Q3 = bl[448];
        for (int g = 0; g < 16; ++g) {
            f16x8 sv = *(const f16x8*)&xp[rm + g * 8];   // splat plane = x0
#pragma unroll
            for (int jj = 0; jj < 8; ++jj) {
                int u = g * 8 + jj;
                size_t nb = (size_t)(u + 1 < 128 ? u + 1 : 127) * 512;
                f16x8 sp = splat8(sv[jj]);
                acc = mfma32(sp * va[0], as_h8(P0), acc);
                acc = mfma32(sp * va[1], as_h8(P1), acc);
                acc = mfma32(sp * va[2], as_h8(P2), acc);
                acc = mfma32(sp * va[3], as_h8(P3), acc);
                P0 = bl[nb]; P1 = bl[nb + 64]; P2 = bl[nb + 128]; P3 = bl[nb + 192];
                acc = mfma32(sp * va[4], as_h8(Q0), acc);
                acc = mfma32(sp * va[5], as_h8(Q1), acc);
                acc = mfma32(sp * va[6], as_h8(Q2), acc);
                acc = mfma32(sp * va[7], as_h8(Q3), acc);
                Q0 = bl[nb + 256]; Q1 = bl[nb + 320]; Q2 = bl[nb + 384]; Q3 = bl[nb + 448];
            }
        }
        writeT32(raw, cidx, zb * 64 + mg * 32, hq * 32, l31, lk, acc);
    } else {
        // ---- vv (w2-3): 4 passes x 2 segs, 3-plane A-build ----
        int mg = w - 2;
        const int rm = (mg * 32 + l31) * PSTR;
        const f16* p1 = xp + PLSZ;
        const f16* p2 = xp + 2 * PLSZ;
        const f16* p3 = xp + 3 * PLSZ;
        const uint4* bl = (const uint4*)(wstream + WSTREAM_F16_PER_C
                                         + (size_t)hq * HQSL) + lane;
        f32x16 acc = {};
#pragma unroll 1
        for (int pass = 0; pass < 4; ++pass) {
            int s0 = pass * 2;
            int boff = s0 * 64;
            f16x8 va0[3], va1[3];
#pragma unroll
            for (int p = 0; p < 3; ++p) {
                const f16* pp = xp + (1 + p) * PLSZ;
                va0[p] = *(const f16x8*)&pp[rm + s0 * 16 + lk * 8];
                va1[p] = *(const f16x8*)&pp[rm + (s0 + 1) * 16 + lk * 8];
            }
            uint4 Pa = bl[boff],       Pb = bl[boff + 64];        // u even
            uint4 Qa = bl[512 + boff], Qb = bl[512 + boff + 64];  // u odd
            for (int g = 0; g < 16; ++g) {
                f16x8 s1v = *(const f16x8*)&p1[rm + g * 8];
                f16x8 s2v = *(const f16x8*)&p2[rm + g * 8];
                f16x8 s3v = *(const f16x8*)&p3[rm + g * 8];
#pragma unroll
                for (int jj = 0; jj < 8; jj += 2) {
                    int u = g * 8 + jj;
                    {
                        f16x8 a0 = splat8(s1v[jj]) * va0[0] + splat8(s2v[jj]) * va0[1]
                                 + splat8(s3v[jj]) * va0[2];
                        f16x8 a1 = splat8(s1v[jj]) * va1[0] + splat8(s2v[jj]) * va1[1]
                                 + splat8(s3v[jj]) * va1[2];
                        acc = mfma32(a0, as_h8(Pa), acc);
                        acc = mfma32(a1, as_h8(Pb), acc);
                        size_t nb = (size_t)(u + 2 < 128 ? u + 2 : 126) * 512 + boff;
                        Pa = bl[nb]; Pb = bl[nb + 64];
                    }
                    {
                        f16x8 a0 = splat8(s1v[jj + 1]) * va0[0] + splat8(s2v[jj + 1]) * va0[1]
                                 + splat8(s3v[jj + 1]) * va0[2];
                        f16x8 a1 = splat8(s1v[jj + 1]) * va1[0] + splat8(s2v[jj + 1]) * va1[1]
                                 + splat8(s3v[jj + 1]) * va1[2];
                        acc = mfma32(a0, as_h8(Qa), acc);
                        acc = mfma32(a1, as_h8(Qb), acc);
                        size_t nb = (size_t)(u + 3 < 128 ? u + 3 : 127) * 512 + boff;
                        Qa = bl[nb]; Qb = bl[nb + 64];
                    }
                }
            }
        }
        writeT32(raw, 1, zb * 64 + mg * 32, hq * 32, l31, lk, acc);
    }
}

// ---------------- finalize (unchanged) ----------------
__global__ __launch_bounds__(64) void si_finalize(const float* __restrict__ raw,
                                                  float* __restrict__ out) {
    const float PW0 = 0.0055242717280199f;   // 1/sqrt(2*128*128) == pw1/sqrt(3)
    int z = blockIdx.x;
    int t = threadIdx.x;
    const size_t CS = (size_t)NBATCH * 128;
    const float* r0 = raw + (size_t)z * 128;

    float y0A = PW0 * (r0[t] + r0[CS + t]);
    float y0B = PW0 * (r0[t + 64] + r0[CS + t + 64]);
    float s1 = y0A + y0B, s2 = y0A * y0A + y0B * y0B;
    for (int o = 32; o; o >>= 1) {
        s1 += __shfl_xor(s1, o);
        s2 += __shfl_xor(s2, o);
    }
    float mean = s1 * (1.0f / 128.0f);
    float var = (s2 - 128.0f * mean * mean) * (1.0f / 127.0f);
    float sc = 1.0f / (sqrtf(fmaxf(var, 0.0f)) + 1e-9f);
    out[(size_t)z * 512 + t] = y0A * sc;
    out[(size_t)z * 512 + t + 64] = y0B * sc;

    float yA[3], yB[3];
    float nA = 1e-9f, nB = 1e-9f;
#pragma unroll
    for (int k = 0; k < 3; ++k) {
        yA[k] = PW0 * r0[CS * (2 + k) + t];
        yB[k] = PW0 * r0[CS * (2 + k) + t + 64];
        nA += yA[k] * yA[k];
        nB += yB[k] * yB[k];
    }
    nA = sqrtf(nA);
    nB = sqrtf(nB);
    float t1 = nA + nB, t2 = nA * nA + nB * nB;
    for (int o = 32; o; o >>= 1) {
        t1 += __shfl_xor(t1, o);
        t2 += __shfl_xor(t2, o);
    }
    float meanv = t1 * (1.0f / 128.0f);
    float varv = (t2 - 128.0f * meanv * meanv) * (1.0f / 127.0f);
    float sv = 1.0f / (sqrtf(fmaxf(varv, 0.0f)) + 1e-9f);
#pragma unroll
    for (int k = 0; k < 3; ++k) {
        out[(size_t)z * 512 + 128 + t * 3 + k] = yA[k] * sv;
        out[(size_t)z * 512 + 128 + (t + 64) * 3 + k] = yB[k] * sv;
    }
}

extern "C" void kernel_launch(void* const* d_in, const int* in_sizes, int n_in,
                              void* d_out, int out_size, void* d_ws, size_t ws_size,
                              hipStream_t stream) {
    const float* x = (const float*)d_in[0];
    const float* Wss = (const float*)d_in[1];
    const float* Wvv = (const float*)d_in[2];
    const float* Wsv = (const float*)d_in[3];
    const float* Wvs = (const float*)d_in[4];
    f16* wstream = (f16*)d_ws;
    float* raw = (float*)((char*)d_ws + RAW_OFF_BYTES);
    float* out = (float*)d_out;

    hipLaunchKernelGGL(prep_weights, dim3(384), dim3(256), 0, stream,
                       Wss, Wvv, Wsv, Wvs, wstream);
    hipLaunchKernelGGL(si_main, dim3(512), dim3(640), 0, stream, x, wstream, raw);
    hipLaunchKernelGGL(si_finalize, dim3(NBATCH), dim3(64), 0, stream, raw, out);
}